// Round 10
// baseline (100.105 us; speedup 1.0000x reference)
//
#include <hip/hip_runtime.h>

// LIF multi-step: spikes[t] = Heaviside(h[t] - 1.0), h[t] = 0.5*v + 0.25 + x[t],
// v' = s ? 0.5 : h.  T=64, B=32, N=32768. Memory-bound streaming scan.
//
// R9: force the 16-deep load burst that R7 intended. R7/R8 VGPR_Count=36
// proves the compiler collapsed the batch (16xf4 needs 64 VGPRs) back into an
// interleaved load/store chain -> the R/W-turnaround experiment never ran.
// sched_barrier(0) between the load loop and compute/store loop pins program
// order: 16 back-to-back 1KiB/wave reads, then 16 back-to-back writes.
// Partition dropped (R8: zero effect on FETCH). Plain loads + nt stores kept.

#define T_STEPS 64
#define BATCH 16

typedef float f4 __attribute__((ext_vector_type(4)));

__global__ __launch_bounds__(256, 4) void lif_kernel(const f4* __restrict__ x,
                                                     f4* __restrict__ out,
                                                     int bn4) {
    int idx = blockIdx.x * blockDim.x + threadIdx.x;
    if (idx >= bn4) return;

    const f4* __restrict__ xp = x + idx;
    f4* __restrict__ op = out + idx;

    f4 v = {0.5f, 0.5f, 0.5f, 0.5f};

    #pragma unroll
    for (int c = 0; c < T_STEPS / BATCH; ++c) {
        f4 xt[BATCH];
        #pragma unroll
        for (int i = 0; i < BATCH; ++i)
            xt[i] = xp[(size_t)i * bn4];

        // Pin order: all 16 loads issue before any compute/store below.
        __builtin_amdgcn_sched_barrier(0);

        #pragma unroll
        for (int i = 0; i < BATCH; ++i) {
            float hx = fmaf(0.5f, v.x, 0.25f + xt[i].x);
            float hy = fmaf(0.5f, v.y, 0.25f + xt[i].y);
            float hz = fmaf(0.5f, v.z, 0.25f + xt[i].z);
            float hw = fmaf(0.5f, v.w, 0.25f + xt[i].w);

            f4 s;
            s.x = (hx >= 1.0f) ? 1.0f : 0.0f;
            s.y = (hy >= 1.0f) ? 1.0f : 0.0f;
            s.z = (hz >= 1.0f) ? 1.0f : 0.0f;
            s.w = (hw >= 1.0f) ? 1.0f : 0.0f;

            v.x = (hx >= 1.0f) ? 0.5f : hx;
            v.y = (hy >= 1.0f) ? 0.5f : hy;
            v.z = (hz >= 1.0f) ? 0.5f : hz;
            v.w = (hw >= 1.0f) ? 0.5f : hw;

            __builtin_nontemporal_store(s, op + (size_t)i * bn4);
        }

        xp += (size_t)BATCH * bn4;
        op += (size_t)BATCH * bn4;
    }
}

extern "C" void kernel_launch(void* const* d_in, const int* in_sizes, int n_in,
                              void* d_out, int out_size, void* d_ws, size_t ws_size,
                              hipStream_t stream) {
    const f4* x = (const f4*)d_in[0];
    f4* out = (f4*)d_out;

    int total = in_sizes[0];
    int bn = total / T_STEPS;
    int bn4 = bn / 4;

    int block = 256;
    int grid = (bn4 + block - 1) / block;
    lif_kernel<<<grid, block, 0, stream>>>(x, out, bn4);
}